// Round 12
// baseline (3116.317 us; speedup 1.0000x reference)
//
#include <hip/hip_runtime.h>

#define N_NODES 10000
#define N_EDGES 160000
#define IN_DIM 128
#define HID 16
#define HEADS 50
#define OUT_DIM 10
#define N_GRAPHS 8
#define NHID (HEADS * HID) /* 800 */

// 8 head-groups: grp g owns heads [hstart(g), hstart(g+1)), 6 or 7 heads.
static __device__ __forceinline__ int hstart_of(int g) { return (g * 25) >> 2; }

typedef __attribute__((ext_vector_type(8))) short bfrag;   // 8 bf16 (4 VGPRs)
typedef __attribute__((ext_vector_type(4))) float ffrag;   // 4 fp32 acc

#define LOG2E 1.44269504088896340736f

// ---- bf16 helpers (self-contained, RNE) ----
static __device__ __forceinline__ unsigned short f2bf(float f) {
    union { float f; unsigned u; } v; v.f = f;
    unsigned u = v.u;
    unsigned r = (u + 0x7fffu + ((u >> 16) & 1u)) >> 16;
    return (unsigned short)r;
}
static __device__ __forceinline__ float bits2f(unsigned u) {
    union { unsigned u; float f; } v; v.u = u;
    return v.f;
}

static __device__ __forceinline__ void spin_until_ge(int* p, int target) {
    while (__hip_atomic_load(p, __ATOMIC_ACQUIRE, __HIP_MEMORY_SCOPE_AGENT) < target)
        __builtin_amdgcn_s_sleep(8);
}

// ================= K1: prep (xcast|wcast|hsum0|count) + MFMA GEMM, fused =================
// blocks [0,1250): xbf=bf16(x); [1250,1650): wt transpose; [1650,1807): hsum=0;
// [1807,2432): cnt[dst]++ ; [2432,3222): gemm (spin until the 1650 cast blocks done).
// Deadlock-safe: spinning gemm waves = 790*4 = 3160 < 8192 wave capacity.
__global__ __launch_bounds__(256) void prep_gemm(const float* __restrict__ x,
                                                 const float* __restrict__ W,
                                                 const int* __restrict__ ei,
                                                 unsigned short* __restrict__ xbf,
                                                 unsigned short* __restrict__ wt,
                                                 float* __restrict__ hsum,
                                                 int* __restrict__ cnt,
                                                 int* __restrict__ flags,
                                                 const float* __restrict__ a_src,
                                                 const float* __restrict__ a_dst,
                                                 unsigned short* __restrict__ xpg,
                                                 float* __restrict__ astp,
                                                 float* __restrict__ adtp) {
    const int bid = blockIdx.x, tid = threadIdx.x;
    if (bid < 2432) {
        if (bid < 1250) {
            int t = bid * 256 + tid;  // exactly 320000
            float4 v = ((const float4*)x)[t];
            ushort4 o;
            o.x = f2bf(v.x); o.y = f2bf(v.y); o.z = f2bf(v.z); o.w = f2bf(v.w);
            ((ushort4*)xbf)[t] = o;
        } else if (bid < 1650) {
            int t = (bid - 1250) * 256 + tid;  // exactly 102400
            int n = t >> 7, k = t & 127;
            wt[t] = f2bf(W[k * NHID + n]);
        } else if (bid < 1807) {
            int t = (bid - 1650) * 256 + tid;
            if (t < 40000) ((float4*)hsum)[t] = make_float4(0.f, 0.f, 0.f, 0.f);
        } else {
            int e = (bid - 1807) * 256 + tid;
            if (e < N_EDGES) atomicAdd(&cnt[ei[N_EDGES + e]], 1);
        }
        if (bid < 1650) {  // cast blocks gate the gemm
            __threadfence();
            __syncthreads();
            if (tid == 0)
                __hip_atomic_fetch_add(&flags[0], 1, __ATOMIC_RELEASE, __HIP_MEMORY_SCOPE_AGENT);
        }
        return;
    }
    // ---- gemm part ----
    spin_until_ge(&flags[0], 1650);
    const int b = bid - 2432;  // 0..789
    const int by = b / 10, bx = b - by * 10;
    const int wave = tid >> 6, lane = tid & 63;
    const int q = lane >> 4, r = lane & 15;
    const int m0 = by * 128 + wave * 32;
    const int h0 = bx * 5;
    ffrag zf = {0.f, 0.f, 0.f, 0.f};
    ffrag acc[2][5];
#pragma unroll
    for (int mt = 0; mt < 2; mt++)
#pragma unroll
        for (int nt = 0; nt < 5; nt++) acc[mt][nt] = zf;
#pragma unroll
    for (int kc = 0; kc < IN_DIM; kc += 32) {
        bfrag a[2], bb[5];
#pragma unroll
        for (int mt = 0; mt < 2; mt++)
            a[mt] = *(const bfrag*)(xbf + (m0 + mt * 16 + r) * IN_DIM + kc + q * 8);
#pragma unroll
        for (int nt = 0; nt < 5; nt++)
            bb[nt] = *(const bfrag*)(wt + ((h0 + nt) * 16 + r) * IN_DIM + kc + q * 8);
#pragma unroll
        for (int mt = 0; mt < 2; mt++)
#pragma unroll
            for (int nt = 0; nt < 5; nt++)
                acc[mt][nt] = __builtin_amdgcn_mfma_f32_16x16x32_bf16(a[mt], bb[nt],
                                                                      acc[mt][nt], 0, 0, 0);
    }
#pragma unroll
    for (int nt = 0; nt < 5; nt++) {
        const int h = h0 + nt;
        const int g = (8 * h + 7) / 50;
        const int hl = h - hstart_of(g);
        const float asw = a_src[h * HID + r] * LOG2E;
        const float adw = a_dst[h * HID + r] * LOG2E;
        unsigned short* xg = xpg + (size_t)g * (N_NODES * 128);
        float* ag = astp + g * (N_NODES * 8);
        float* dg = adtp + g * (N_NODES * 8);
#pragma unroll
        for (int mt = 0; mt < 2; mt++) {
            ffrag d = acc[mt][nt];  // rows m = m0+mt*16+q*4+i, col r
            float s[4], w[4];
#pragma unroll
            for (int i = 0; i < 4; i++) { s[i] = d[i] * asw; w[i] = d[i] * adw; }
#pragma unroll
            for (int off = 1; off < 16; off <<= 1) {
#pragma unroll
                for (int i = 0; i < 4; i++) {
                    s[i] += __shfl_xor(s[i], off);
                    w[i] += __shfl_xor(w[i], off);
                }
            }
#pragma unroll
            for (int i = 0; i < 4; i++) {
                const int node = m0 + mt * 16 + q * 4 + i;
                if (node < N_NODES) {
                    xg[node * 128 + hl * 16 + r] = f2bf(d[i]);
                    if (r == 0) {
                        ag[(node << 3) + hl] = s[i];
                        dg[(node << 3) + hl] = w[i];
                    }
                }
            }
        }
    }
}

// ================= K2: scan (block 665) + scatter/degscatter (blocks 0..664), fused =======
// 666 blocks x 4 waves = 2664 waves -> all co-resident; spin is deadlock-free.
__global__ __launch_bounds__(256) void scan_scatter(const int* __restrict__ ei,
                                                    const int* __restrict__ cnt,
                                                    int* __restrict__ offs,
                                                    int* __restrict__ curs,
                                                    int* __restrict__ dcur,
                                                    int* __restrict__ ssrc,
                                                    int* __restrict__ perm,
                                                    int* __restrict__ flags) {
    const int bid = blockIdx.x, t = threadIdx.x;
    if (bid == 665) {
        // ---- scan: 256 threads x 40 elems ----
        __shared__ int wsum[4];
        __shared__ int dh[64];
        const int lane = t & 63, wid = t >> 6;
        if (t < 64) dh[t] = 0;
        __syncthreads();
        const int base = t * 40;
        int local[40];
        int s = 0;
#pragma unroll
        for (int i = 0; i < 40; i++) {
            int idx = base + i;
            int v = (idx < N_NODES) ? cnt[idx] : 0;
            if (idx < N_NODES) { int bb = v < 63 ? v : 63; atomicAdd(&dh[63 - bb], 1); }
            local[i] = s;
            s += v;
        }
        int incl = s;
#pragma unroll
        for (int off = 1; off < 64; off <<= 1) {
            int u = __shfl_up(incl, off);
            if (lane >= off) incl += u;
        }
        if (lane == 63) wsum[wid] = incl;
        __syncthreads();
        if (wid == 0 && lane < 4) {
            int v = wsum[lane];
            int i2 = v;
#pragma unroll
            for (int off = 1; off < 4; off <<= 1) {
                int u = __shfl_up(i2, off);
                if (lane >= off) i2 += u;
            }
            wsum[lane] = i2 - v;  // exclusive wave offset
        }
        __syncthreads();
        const int texcl = (incl - s) + wsum[wid];
#pragma unroll
        for (int i = 0; i < 40; i++) {
            int idx = base + i;
            if (idx < N_NODES) {
                int o = texcl + local[i];
                offs[idx] = o;
                curs[idx] = o;
            }
        }
        if (t == 255) offs[N_NODES] = texcl + s;  // == N_EDGES
        __syncthreads();
        if (wid == 0) {
            int v = dh[lane];
            int i3 = v;
#pragma unroll
            for (int off = 1; off < 64; off <<= 1) {
                int u = __shfl_up(i3, off);
                if (lane >= off) i3 += u;
            }
            dcur[lane] = i3 - v;  // exclusive (descending-degree bins)
        }
        __threadfence();
        __syncthreads();
        if (t == 0)
            __hip_atomic_store(&flags[1], 1, __ATOMIC_RELEASE, __HIP_MEMORY_SCOPE_AGENT);
        return;
    }
    spin_until_ge(&flags[1], 1);
    if (bid < 625) {
        int e = bid * 256 + t;
        if (e < N_EDGES) {
            int d = ei[N_EDGES + e];
            int pos = atomicAdd(&curs[d], 1);
            ssrc[pos] = ei[e];
        }
    } else {
        int n = (bid - 625) * 256 + t;
        if (n < N_NODES) {
            int d = cnt[n];
            d = d < 63 ? d : 63;
            int pos = atomicAdd(&dcur[63 - d], 1);  // descending degree
            perm[pos] = n;
        }
    }
}

// ================= K3: chunk-deduped aggregation + last-block pool/FC, fused ==============
__global__ __launch_bounds__(256) void agg_pool(const unsigned short* __restrict__ xpg,
                                                const float* __restrict__ astp,
                                                const float* __restrict__ adtp,
                                                const int* __restrict__ offs,
                                                const int* __restrict__ ssrc,
                                                const int* __restrict__ perm,
                                                float* __restrict__ hsum,
                                                int* __restrict__ flags,
                                                const int* __restrict__ batch,
                                                const float* __restrict__ bias,
                                                const float* __restrict__ fc_w,
                                                const float* __restrict__ fc_b,
                                                float* __restrict__ out) {
    __shared__ float red[256][17];
    __shared__ float pooled[16];
    __shared__ int ticket_s;
    const int t = threadIdx.x;
    const int wave = t >> 6, lane = t & 63;
    const int g = blockIdx.x & 7;
    const int db = blockIdx.x >> 3;  // 0..2499
    const int cg = hstart_of(g + 1) - hstart_of(g);  // 6 or 7
    const int hl = lane >> 3;
    const int esub = lane & 7;
    const int co = (hl << 4) + esub * 2;
    const int wbase = lane & 56;
    const int dst = __builtin_amdgcn_readfirstlane(perm[db * 4 + wave]);
    const int start = __builtin_amdgcn_readfirstlane(offs[dst]);
    const int eend = __builtin_amdgcn_readfirstlane(offs[dst + 1]);
    const float* ag = astp + g * (N_NODES * 8);
    const unsigned short* xg = xpg + (size_t)g * (N_NODES * 128);
    const float adv = adtp[g * (N_NODES * 8) + (dst << 3) + hl];
    // self loop
    float lS = ag[(dst << 3) + hl] + adv;
    lS = fmaxf(lS, 0.2f * lS);
    const float wS = exp2f(lS);
    const unsigned pS = *(const unsigned*)(xg + (dst << 7) + co);
    float den = wS;
    float acc0 = wS * bits2f(pS << 16);
    float acc1 = wS * bits2f(pS & 0xffff0000u);
    const int elast = eend - 1;
    for (int base = start; base < eend; base += 8) {
        const int eidx = base + esub;
        const int ecl = (eidx < elast) ? eidx : elast;
        const int sE = ssrc[ecl];
        float l = ag[(sE << 3) + hl] + adv;
        l = fmaxf(l, 0.2f * l);
        const float w = (eidx < eend) ? exp2f(l) : 0.f;
#pragma unroll
        for (int j = 0; j < 8; j++) {
            const int ej = (base + j < elast) ? (base + j) : elast;
            const int sj = __builtin_amdgcn_readfirstlane(ssrc[ej]);
            const float wj = __shfl(w, wbase + j);
            const unsigned p = *(const unsigned*)(xg + (sj << 7) + co);
            den += wj;
            acc0 = fmaf(wj, bits2f(p << 16), acc0);
            acc1 = fmaf(wj, bits2f(p & 0xffff0000u), acc1);
        }
    }
    const float inv = (hl < cg) ? (1.f / den) : 0.f;
    float v0 = acc0 * inv, v1 = acc1 * inv;
    v0 += __shfl_xor(v0, 8);  v1 += __shfl_xor(v1, 8);
    v0 += __shfl_xor(v0, 16); v1 += __shfl_xor(v1, 16);
    v0 += __shfl_xor(v0, 32); v1 += __shfl_xor(v1, 32);
    if (lane < 8) {
        atomicAdd(&hsum[(dst << 4) + 2 * lane + 0], v0);
        atomicAdd(&hsum[(dst << 4) + 2 * lane + 1], v1);
    }
    // ---- completion ticket; last block pools all graphs ----
    __threadfence();
    __syncthreads();
    if (t == 0)
        ticket_s = __hip_atomic_fetch_add(&flags[2], 1, __ATOMIC_ACQ_REL,
                                          __HIP_MEMORY_SCOPE_AGENT);
    __syncthreads();
    if (ticket_s != 8 * (N_NODES / 4) - 1) return;
    for (int gg = 0; gg < N_GRAPHS; gg++) {
        int a = 0, b = N_NODES;
        while (a < b) { int m = (a + b) >> 1; if (batch[m] < gg) a = m + 1; else b = m; }
        const int lo = a;
        b = N_NODES;
        while (a < b) { int m = (a + b) >> 1; if (batch[m] < gg + 1) a = m + 1; else b = m; }
        const int hi = a;
        const int cntn = hi - lo;
        float acc[16];
#pragma unroll
        for (int c = 0; c < 16; c++) acc[c] = 0.f;
        for (int n = lo + t; n < hi; n += 256) {
            const float4* r = (const float4*)(hsum + (n << 4));
            float4 q0 = r[0], q1 = r[1], q2 = r[2], q3 = r[3];
            acc[0] += q0.x; acc[1] += q0.y; acc[2] += q0.z; acc[3] += q0.w;
            acc[4] += q1.x; acc[5] += q1.y; acc[6] += q1.z; acc[7] += q1.w;
            acc[8] += q2.x; acc[9] += q2.y; acc[10] += q2.z; acc[11] += q2.w;
            acc[12] += q3.x; acc[13] += q3.y; acc[14] += q3.z; acc[15] += q3.w;
        }
#pragma unroll
        for (int c = 0; c < 16; c++) red[t][c] = acc[c];
        __syncthreads();
        for (int s = 128; s > 0; s >>= 1) {
            if (t < s)
#pragma unroll
                for (int c = 0; c < 16; c++) red[t][c] += red[t + s][c];
            __syncthreads();
        }
        if (t < 16) {
            float v = 0.f;
            if (cntn > 0) v = red[0][t] / ((float)cntn * (float)HEADS) + bias[t];
            pooled[t] = v;
        }
        __syncthreads();
        if (t < OUT_DIM) {
            float s = fc_b[t];
#pragma unroll
            for (int c = 0; c < HID; c++) s += pooled[c] * fc_w[c * OUT_DIM + t];
            out[gg * OUT_DIM + t] = s;
        }
        __syncthreads();
    }
}

// ---- workspace layout (bytes) ----
#define XPG_OFF 0              /* 8*10000*8*16*2 = 20,480,000 */
#define ASTP_OFF 20480000      /* 8*10000*8*4    =  2,560,000 */
#define ADTP_OFF 23040000      /* 8*10000*8*4    =  2,560,000 */
#define XBF_OFF 25600000       /* 10000*128*2    =  2,560,000 (wt follows: OOB-read safe) */
#define WT_OFF 28160000        /* 800*128*2      =    204,800 */
#define SSRC_OFF 28364800      /* 160000*4       =    640,000 */
#define OFFS_OFF 29004800      /* 10001*4        =     40,064 padded */
#define CURS_OFF 29044864      /* 10000*4        =     40,000 */
#define PERM_OFF 29084864      /* 10000*4        =     40,000 */
#define HSUM_OFF 29124864      /* 10000*16*4     =    640,000 (zeroed in prep) */
#define CNT_OFF 29764864       /* 10000*4        =     40,000 (zeroed by memset) */
#define FLAGS_OFF 29804864     /* 3*4 pad 64     (zeroed by memset) */
#define DCUR_OFF 29804928      /* 64*4           =        256 */

extern "C" void kernel_launch(void* const* d_in, const int* in_sizes, int n_in,
                              void* d_out, int out_size, void* d_ws, size_t ws_size,
                              hipStream_t stream) {
    const float* x = (const float*)d_in[0];
    const int* ei = (const int*)d_in[1];
    const int* batch = (const int*)d_in[2];
    const float* W = (const float*)d_in[4];
    const float* a_src = (const float*)d_in[5];
    const float* a_dst = (const float*)d_in[6];
    const float* bias = (const float*)d_in[7];
    const float* fc_w = (const float*)d_in[8];
    const float* fc_b = (const float*)d_in[9];
    float* out = (float*)d_out;

    char* ws = (char*)d_ws;
    unsigned short* xpg = (unsigned short*)(ws + XPG_OFF);
    float* astp = (float*)(ws + ASTP_OFF);
    float* adtp = (float*)(ws + ADTP_OFF);
    unsigned short* xbf = (unsigned short*)(ws + XBF_OFF);
    unsigned short* wt = (unsigned short*)(ws + WT_OFF);
    int* ssrc = (int*)(ws + SSRC_OFF);
    int* offs = (int*)(ws + OFFS_OFF);
    int* curs = (int*)(ws + CURS_OFF);
    int* perm = (int*)(ws + PERM_OFF);
    float* hsum = (float*)(ws + HSUM_OFF);
    int* cntc = (int*)(ws + CNT_OFF);
    int* flags = (int*)(ws + FLAGS_OFF);
    int* dcur = (int*)(ws + DCUR_OFF);

    hipMemsetAsync(ws + CNT_OFF, 0, 40064, stream);  // cnt + flags
    prep_gemm<<<3222, 256, 0, stream>>>(x, W, ei, xbf, wt, hsum, cntc, flags,
                                        a_src, a_dst, xpg, astp, adtp);
    scan_scatter<<<666, 256, 0, stream>>>(ei, cntc, offs, curs, dcur, ssrc, perm, flags);
    agg_pool<<<8 * (N_NODES / 4), 256, 0, stream>>>(xpg, astp, adtp, offs, ssrc, perm, hsum,
                                                    flags, batch, bias, fc_w, fc_b, out);
}

// Round 13
// 184.380 us; speedup vs baseline: 16.9016x; 16.9016x over previous
//
#include <hip/hip_runtime.h>

#define N_NODES 10000
#define N_EDGES 160000
#define IN_DIM 128
#define HID 16
#define HEADS 50
#define OUT_DIM 10
#define N_GRAPHS 8
#define NHID (HEADS * HID) /* 800 */
#define ECAP 64  /* bucket capacity per dst; Poisson(16), P(deg>63) ~ 1e-20 */

// 8 head-groups: grp g owns heads [hstart(g), hstart(g+1)), 6 or 7 heads.
static __device__ __forceinline__ int hstart_of(int g) { return (g * 25) >> 2; }

typedef __attribute__((ext_vector_type(8))) short bfrag;   // 8 bf16 (4 VGPRs)
typedef __attribute__((ext_vector_type(4))) float ffrag;   // 4 fp32 acc

#define LOG2E 1.44269504088896340736f

// ---- bf16 helpers (self-contained, RNE) ----
static __device__ __forceinline__ unsigned short f2bf(float f) {
    union { float f; unsigned u; } v; v.f = f;
    unsigned u = v.u;
    unsigned r = (u + 0x7fffu + ((u >> 16) & 1u)) >> 16;
    return (unsigned short)r;
}
static __device__ __forceinline__ float bits2f(unsigned u) {
    union { unsigned u; float f; } v; v.u = u;
    return v.f;
}

// ---- K0: fused parallel prep: xcast | wcast(transpose) | hsum zero | edge APPEND ----
// blocks [0,1250): xbf = bf16(x)                (320000 float4s)
// blocks [1250,1650): wt[n][k] = bf16(W[k][n])  (102400 elems)
// blocks [1650,1807): hsum = 0                  (40000 float4s)
// blocks [1807,2432): ebuf[dst*64 + slot] = src (slot = atomicAdd(cnt[dst],1))
// Single-pass CSR replacement: no scan, no scatter dispatch.
__global__ __launch_bounds__(256) void prep_kernel(const float* __restrict__ x,
                                                   const float* __restrict__ W,
                                                   const int* __restrict__ ei,
                                                   unsigned short* __restrict__ xbf,
                                                   unsigned short* __restrict__ wt,
                                                   float* __restrict__ hsum,
                                                   int* __restrict__ cnt,
                                                   int* __restrict__ ebuf) {
    const int bid = blockIdx.x, tid = threadIdx.x;
    if (bid < 1250) {
        int t = bid * 256 + tid;  // exactly 320000
        float4 v = ((const float4*)x)[t];
        ushort4 o;
        o.x = f2bf(v.x); o.y = f2bf(v.y); o.z = f2bf(v.z); o.w = f2bf(v.w);
        ((ushort4*)xbf)[t] = o;
    } else if (bid < 1650) {
        int t = (bid - 1250) * 256 + tid;  // exactly 102400
        int n = t >> 7, k = t & 127;
        wt[t] = f2bf(W[k * NHID + n]);
    } else if (bid < 1807) {
        int t = (bid - 1650) * 256 + tid;
        if (t < 40000) ((float4*)hsum)[t] = make_float4(0.f, 0.f, 0.f, 0.f);
    } else {
        int e = (bid - 1807) * 256 + tid;
        if (e < N_EDGES) {
            int d = ei[N_EDGES + e];
            int slot = atomicAdd(&cnt[d], 1);
            if (slot < ECAP) ebuf[(d << 6) + slot] = ei[e];  // guard: no OOB ever
        }
    }
}

// ---- K1: MFMA bf16 GEMM, LDS-free, alpha fused (pre-scaled by log2e) ----
// grid (10, 79), block 256 = 4 waves; wave: 32 rows x 80 cols = 2x5 tiles.
__global__ __launch_bounds__(256) void gemm_mfma(const unsigned short* __restrict__ xbf,
                                                 const unsigned short* __restrict__ wt,
                                                 const float* __restrict__ a_src,
                                                 const float* __restrict__ a_dst,
                                                 unsigned short* __restrict__ xpg,
                                                 float* __restrict__ astp,
                                                 float* __restrict__ adtp) {
    const int tid = threadIdx.x;
    const int wave = tid >> 6, lane = tid & 63;
    const int q = lane >> 4, r = lane & 15;
    const int m0 = blockIdx.y * 128 + wave * 32;
    const int h0 = blockIdx.x * 5;
    ffrag zf = {0.f, 0.f, 0.f, 0.f};
    ffrag acc[2][5];
#pragma unroll
    for (int mt = 0; mt < 2; mt++)
#pragma unroll
        for (int nt = 0; nt < 5; nt++) acc[mt][nt] = zf;

    // A reads may overrun past node 9999 (stores guarded); xbf is followed by
    // wt in the workspace so reads stay inside the allocation.
#pragma unroll
    for (int kc = 0; kc < IN_DIM; kc += 32) {
        bfrag a[2], b[5];
#pragma unroll
        for (int mt = 0; mt < 2; mt++)
            a[mt] = *(const bfrag*)(xbf + (m0 + mt * 16 + r) * IN_DIM + kc + q * 8);
#pragma unroll
        for (int nt = 0; nt < 5; nt++)
            b[nt] = *(const bfrag*)(wt + ((h0 + nt) * 16 + r) * IN_DIM + kc + q * 8);
#pragma unroll
        for (int mt = 0; mt < 2; mt++)
#pragma unroll
            for (int nt = 0; nt < 5; nt++)
                acc[mt][nt] = __builtin_amdgcn_mfma_f32_16x16x32_bf16(a[mt], b[nt],
                                                                      acc[mt][nt], 0, 0, 0);
    }
#pragma unroll
    for (int nt = 0; nt < 5; nt++) {
        const int h = h0 + nt;
        const int g = (8 * h + 7) / 50;
        const int hl = h - hstart_of(g);
        const float asw = a_src[h * HID + r] * LOG2E;
        const float adw = a_dst[h * HID + r] * LOG2E;
        unsigned short* xg = xpg + (size_t)g * (N_NODES * 128);
        float* ag = astp + g * (N_NODES * 8);
        float* dg = adtp + g * (N_NODES * 8);
#pragma unroll
        for (int mt = 0; mt < 2; mt++) {
            ffrag d = acc[mt][nt];  // rows m = m0+mt*16+q*4+i, col r
            float s[4], w[4];
#pragma unroll
            for (int i = 0; i < 4; i++) { s[i] = d[i] * asw; w[i] = d[i] * adw; }
#pragma unroll
            for (int off = 1; off < 16; off <<= 1) {
#pragma unroll
                for (int i = 0; i < 4; i++) {
                    s[i] += __shfl_xor(s[i], off);
                    w[i] += __shfl_xor(w[i], off);
                }
            }
#pragma unroll
            for (int i = 0; i < 4; i++) {
                const int node = m0 + mt * 16 + q * 4 + i;
                if (node < N_NODES) {
                    xg[node * 128 + hl * 16 + r] = f2bf(d[i]);
                    if (r == 0) {
                        ag[(node << 3) + hl] = s[i];
                        dg[(node << 3) + hl] = w[i];
                    }
                }
            }
        }
    }
}

// ---- K4: chunk-deduped aggregation over bucket lists ----
// grid 20000 = 8 grps x 2500 (blockIdx&7 -> XCD; slice L2-resident). Wave owns
// dst = db*4+wave. Edges in chunks of 8: compute phase (lane = (esub, head))
// computes each (edge, head) weight ONCE; accum phase pulls weights via
// __shfl and fmas 2 channels per lane from L2-resident xpg. No barriers.
__global__ __launch_bounds__(256) void agg_kernel(const unsigned short* __restrict__ xpg,
                                                  const float* __restrict__ astp,
                                                  const float* __restrict__ adtp,
                                                  const int* __restrict__ cnt,
                                                  const int* __restrict__ ebuf,
                                                  float* __restrict__ hsum) {
    const int t = threadIdx.x;
    const int wave = t >> 6, lane = t & 63;
    const int g = blockIdx.x & 7;
    const int db = blockIdx.x >> 3;  // 0..2499
    const int cg = hstart_of(g + 1) - hstart_of(g);  // 6 or 7
    const int hl = lane >> 3;
    const int esub = lane & 7;
    const int co = (hl << 4) + esub * 2;  // element offset in 128-wide row
    const int wbase = lane & 56;          // shfl source base = head's lane block
    const int dst = db * 4 + wave;        // 0..9999
    int deg = __builtin_amdgcn_readfirstlane(cnt[dst]);
    deg = (deg < ECAP) ? deg : ECAP;
    const int ebase = dst << 6;
    const float* ag = astp + g * (N_NODES * 8);
    const unsigned short* xg = xpg + (size_t)g * (N_NODES * 128);
    const float adv = adtp[g * (N_NODES * 8) + (dst << 3) + hl];
    // self loop (exp once per (dst, head))
    float lS = ag[(dst << 3) + hl] + adv;
    lS = fmaxf(lS, 0.2f * lS);
    const float wS = exp2f(lS);
    const unsigned pS = *(const unsigned*)(xg + (dst << 7) + co);
    float den = wS;
    float acc0 = wS * bits2f(pS << 16);
    float acc1 = wS * bits2f(pS & 0xffff0000u);
    const int elast = deg - 1;
    for (int base = 0; base < deg; base += 8) {
        // compute phase: w for (edge base+esub, head hl), computed ONCE
        const int eidx = base + esub;
        const int ecl = (eidx < elast) ? eidx : elast;
        const int sE = ebuf[ebase + ecl];
        float l = ag[(sE << 3) + hl] + adv;
        l = fmaxf(l, 0.2f * l);
        const float w = (eidx < deg) ? exp2f(l) : 0.f;
        // accum phase: 8 edges, weights via bpermute, px coalesced from L2
#pragma unroll
        for (int j = 0; j < 8; j++) {
            const int ej = (base + j < elast) ? (base + j) : elast;
            const int sj = __builtin_amdgcn_readfirstlane(ebuf[ebase + ej]);
            const float wj = __shfl(w, wbase + j);
            const unsigned p = *(const unsigned*)(xg + (sj << 7) + co);
            den += wj;
            acc0 = fmaf(wj, bits2f(p << 16), acc0);
            acc1 = fmaf(wj, bits2f(p & 0xffff0000u), acc1);
        }
    }
    const float inv = (hl < cg) ? (1.f / den) : 0.f;  // den>0: self loop
    float v0 = acc0 * inv, v1 = acc1 * inv;
    v0 += __shfl_xor(v0, 8);  v1 += __shfl_xor(v1, 8);
    v0 += __shfl_xor(v0, 16); v1 += __shfl_xor(v1, 16);
    v0 += __shfl_xor(v0, 32); v1 += __shfl_xor(v1, 32);
    if (lane < 8) {
        atomicAdd(&hsum[(dst << 4) + 2 * lane + 0], v0);
        atomicAdd(&hsum[(dst << 4) + 2 * lane + 1], v1);
    }
}

// ---- K5: per-graph mean pool (+ head mean + bias) + FC. One block per graph. ----
__global__ __launch_bounds__(256) void pool_kernel(const float* __restrict__ hsum,
                                                   const int* __restrict__ batch,
                                                   const float* __restrict__ bias,
                                                   const float* __restrict__ fc_w,
                                                   const float* __restrict__ fc_b,
                                                   float* __restrict__ out) {
    const int g = blockIdx.x;
    const int t = threadIdx.x;
    int a = 0, b = N_NODES;
    while (a < b) { int m = (a + b) >> 1; if (batch[m] < g) a = m + 1; else b = m; }
    const int lo = a;
    b = N_NODES;
    while (a < b) { int m = (a + b) >> 1; if (batch[m] < g + 1) a = m + 1; else b = m; }
    const int hi = a;
    const int cntn = hi - lo;
    float acc[16];
#pragma unroll
    for (int c = 0; c < 16; c++) acc[c] = 0.f;
    for (int n = lo + t; n < hi; n += 256) {
        const float4* r = (const float4*)(hsum + (n << 4));
        float4 v0 = r[0], v1 = r[1], v2 = r[2], v3 = r[3];
        acc[0] += v0.x; acc[1] += v0.y; acc[2] += v0.z; acc[3] += v0.w;
        acc[4] += v1.x; acc[5] += v1.y; acc[6] += v1.z; acc[7] += v1.w;
        acc[8] += v2.x; acc[9] += v2.y; acc[10] += v2.z; acc[11] += v2.w;
        acc[12] += v3.x; acc[13] += v3.y; acc[14] += v3.z; acc[15] += v3.w;
    }
    __shared__ float red[256][17];
#pragma unroll
    for (int c = 0; c < 16; c++) red[t][c] = acc[c];
    __syncthreads();
    for (int s = 128; s > 0; s >>= 1) {
        if (t < s)
#pragma unroll
            for (int c = 0; c < 16; c++) red[t][c] += red[t + s][c];
        __syncthreads();
    }
    __shared__ float pooled[16];
    if (t < 16) {
        float v = 0.f;
        if (cntn > 0) v = red[0][t] / ((float)cntn * (float)HEADS) + bias[t];
        pooled[t] = v;
    }
    __syncthreads();
    if (t < OUT_DIM) {
        float s = fc_b[t];
#pragma unroll
        for (int c = 0; c < HID; c++) s += pooled[c] * fc_w[c * OUT_DIM + t];
        out[g * OUT_DIM + t] = s;
    }
}

// ---- workspace layout (bytes) ----
#define XPG_OFF 0              /* 8*10000*8*16*2 = 20,480,000 */
#define ASTP_OFF 20480000      /* 8*10000*8*4    =  2,560,000 */
#define ADTP_OFF 23040000      /* 8*10000*8*4    =  2,560,000 */
#define XBF_OFF 25600000       /* 10000*128*2    =  2,560,000 (wt follows: OOB-read safe) */
#define WT_OFF 28160000        /* 800*128*2      =    204,800 */
#define EBUF_OFF 28364800      /* 10000*64*4     =  2,560,000 */
#define HSUM_OFF 30924800      /* 10000*16*4     =    640,000 (zeroed in prep) */
#define CNT_OFF 31564800       /* 10000*4        =     40,000 (zeroed by memset) */

extern "C" void kernel_launch(void* const* d_in, const int* in_sizes, int n_in,
                              void* d_out, int out_size, void* d_ws, size_t ws_size,
                              hipStream_t stream) {
    const float* x = (const float*)d_in[0];
    const int* ei = (const int*)d_in[1];
    const int* batch = (const int*)d_in[2];
    const float* W = (const float*)d_in[4];
    const float* a_src = (const float*)d_in[5];
    const float* a_dst = (const float*)d_in[6];
    const float* bias = (const float*)d_in[7];
    const float* fc_w = (const float*)d_in[8];
    const float* fc_b = (const float*)d_in[9];
    float* out = (float*)d_out;

    char* ws = (char*)d_ws;
    unsigned short* xpg = (unsigned short*)(ws + XPG_OFF);
    float* astp = (float*)(ws + ASTP_OFF);
    float* adtp = (float*)(ws + ADTP_OFF);
    unsigned short* xbf = (unsigned short*)(ws + XBF_OFF);
    unsigned short* wt = (unsigned short*)(ws + WT_OFF);
    int* ebuf = (int*)(ws + EBUF_OFF);
    float* hsum = (float*)(ws + HSUM_OFF);
    int* cntc = (int*)(ws + CNT_OFF);

    hipMemsetAsync(ws + CNT_OFF, 0, 40000, stream);
    prep_kernel<<<2432, 256, 0, stream>>>(x, W, ei, xbf, wt, hsum, cntc, ebuf);
    gemm_mfma<<<dim3(10, (N_NODES + 127) / 128), 256, 0, stream>>>(
        xbf, wt, a_src, a_dst, xpg, astp, adtp);
    agg_kernel<<<8 * (N_NODES / 4), 256, 0, stream>>>(xpg, astp, adtp, cntc, ebuf, hsum);
    pool_kernel<<<N_GRAPHS, 256, 0, stream>>>(hsum, batch, bias, fc_w, fc_b, out);
}

// Round 15
// 182.843 us; speedup vs baseline: 17.0436x; 1.0084x over previous
//
#include <hip/hip_runtime.h>

#define N_NODES 10000
#define N_EDGES 160000
#define IN_DIM 128
#define HID 16
#define HEADS 50
#define OUT_DIM 10
#define N_GRAPHS 8
#define NHID (HEADS * HID) /* 800 */
#define ECAP 64  /* bucket capacity per dst; Poisson(16), P(deg>63) ~ 1e-20 */

// 8 head-groups: grp g owns heads [hstart(g), hstart(g+1)), 6 or 7 heads.
static __device__ __forceinline__ int hstart_of(int g) { return (g * 25) >> 2; }

typedef __attribute__((ext_vector_type(8))) short bfrag;   // 8 bf16 (4 VGPRs)
typedef __attribute__((ext_vector_type(4))) float ffrag;   // 4 fp32 acc

#define LOG2E 1.44269504088896340736f

// ---- bf16 helpers (self-contained, RNE) ----
static __device__ __forceinline__ unsigned short f2bf(float f) {
    union { float f; unsigned u; } v; v.f = f;
    unsigned u = v.u;
    unsigned r = (u + 0x7fffu + ((u >> 16) & 1u)) >> 16;
    return (unsigned short)r;
}
static __device__ __forceinline__ float bits2f(unsigned u) {
    union { unsigned u; float f; } v; v.u = u;
    return v.f;
}

// ---- K0: fused parallel prep: xcast | wcast(transpose) | hsum zero | edge APPEND ----
// blocks [0,1250): xbf = bf16(x)                (320000 float4s)
// blocks [1250,1650): wt[n][k] = bf16(W[k][n])  (102400 elems)
// blocks [1650,1807): hsum = 0                  (40000 float4s)
// blocks [1807,2432): ebuf[dst*64 + slot] = src (slot = atomicAdd(cnt[dst],1))
// ebuf+cnt pre-zeroed by ONE memset: pad slots = node 0 (valid; weight-masked).
__global__ __launch_bounds__(256) void prep_kernel(const float* __restrict__ x,
                                                   const float* __restrict__ W,
                                                   const int* __restrict__ ei,
                                                   unsigned short* __restrict__ xbf,
                                                   unsigned short* __restrict__ wt,
                                                   float* __restrict__ hsum,
                                                   int* __restrict__ cnt,
                                                   int* __restrict__ ebuf) {
    const int bid = blockIdx.x, tid = threadIdx.x;
    if (bid < 1250) {
        int t = bid * 256 + tid;  // exactly 320000
        float4 v = ((const float4*)x)[t];
        ushort4 o;
        o.x = f2bf(v.x); o.y = f2bf(v.y); o.z = f2bf(v.z); o.w = f2bf(v.w);
        ((ushort4*)xbf)[t] = o;
    } else if (bid < 1650) {
        int t = (bid - 1250) * 256 + tid;  // exactly 102400
        int n = t >> 7, k = t & 127;
        wt[t] = f2bf(W[k * NHID + n]);
    } else if (bid < 1807) {
        int t = (bid - 1650) * 256 + tid;
        if (t < 40000) ((float4*)hsum)[t] = make_float4(0.f, 0.f, 0.f, 0.f);
    } else {
        int e = (bid - 1807) * 256 + tid;
        if (e < N_EDGES) {
            int d = ei[N_EDGES + e];
            int slot = atomicAdd(&cnt[d], 1);
            if (slot < ECAP) ebuf[(d << 6) + slot] = ei[e];  // guard: no OOB ever
        }
    }
}

// ---- K1: MFMA bf16 GEMM, LDS-free, alpha fused (pre-scaled by log2e) ----
// grid (10, 79), block 256 = 4 waves; wave: 32 rows x 80 cols = 2x5 tiles.
__global__ __launch_bounds__(256) void gemm_mfma(const unsigned short* __restrict__ xbf,
                                                 const unsigned short* __restrict__ wt,
                                                 const float* __restrict__ a_src,
                                                 const float* __restrict__ a_dst,
                                                 unsigned short* __restrict__ xpg,
                                                 float* __restrict__ astp,
                                                 float* __restrict__ adtp) {
    const int tid = threadIdx.x;
    const int wave = tid >> 6, lane = tid & 63;
    const int q = lane >> 4, r = lane & 15;
    const int m0 = blockIdx.y * 128 + wave * 32;
    const int h0 = blockIdx.x * 5;
    ffrag zf = {0.f, 0.f, 0.f, 0.f};
    ffrag acc[2][5];
#pragma unroll
    for (int mt = 0; mt < 2; mt++)
#pragma unroll
        for (int nt = 0; nt < 5; nt++) acc[mt][nt] = zf;

    // A reads may overrun past node 9999 (stores guarded); xbf is followed by
    // wt in the workspace so reads stay inside the allocation.
#pragma unroll
    for (int kc = 0; kc < IN_DIM; kc += 32) {
        bfrag a[2], b[5];
#pragma unroll
        for (int mt = 0; mt < 2; mt++)
            a[mt] = *(const bfrag*)(xbf + (m0 + mt * 16 + r) * IN_DIM + kc + q * 8);
#pragma unroll
        for (int nt = 0; nt < 5; nt++)
            b[nt] = *(const bfrag*)(wt + ((h0 + nt) * 16 + r) * IN_DIM + kc + q * 8);
#pragma unroll
        for (int mt = 0; mt < 2; mt++)
#pragma unroll
            for (int nt = 0; nt < 5; nt++)
                acc[mt][nt] = __builtin_amdgcn_mfma_f32_16x16x32_bf16(a[mt], b[nt],
                                                                      acc[mt][nt], 0, 0, 0);
    }
#pragma unroll
    for (int nt = 0; nt < 5; nt++) {
        const int h = h0 + nt;
        const int g = (8 * h + 7) / 50;
        const int hl = h - hstart_of(g);
        const float asw = a_src[h * HID + r] * LOG2E;
        const float adw = a_dst[h * HID + r] * LOG2E;
        unsigned short* xg = xpg + (size_t)g * (N_NODES * 128);
        float* ag = astp + g * (N_NODES * 8);
        float* dg = adtp + g * (N_NODES * 8);
#pragma unroll
        for (int mt = 0; mt < 2; mt++) {
            ffrag d = acc[mt][nt];  // rows m = m0+mt*16+q*4+i, col r
            float s[4], w[4];
#pragma unroll
            for (int i = 0; i < 4; i++) { s[i] = d[i] * asw; w[i] = d[i] * adw; }
#pragma unroll
            for (int off = 1; off < 16; off <<= 1) {
#pragma unroll
                for (int i = 0; i < 4; i++) {
                    s[i] += __shfl_xor(s[i], off);
                    w[i] += __shfl_xor(w[i], off);
                }
            }
#pragma unroll
            for (int i = 0; i < 4; i++) {
                const int node = m0 + mt * 16 + q * 4 + i;
                if (node < N_NODES) {
                    xg[node * 128 + hl * 16 + r] = f2bf(d[i]);
                    if (r == 0) {
                        ag[(node << 3) + hl] = s[i];
                        dg[(node << 3) + hl] = w[i];
                    }
                }
            }
        }
    }
}

// ---- K4: chunk-deduped aggregation over zero-padded bucket lists ----
// grid 20000 = 8 grps x 2500 (blockIdx&7 -> XCD; slice L2-resident). Wave owns
// dst = db*4+wave. Per 8-edge chunk: srcs via two uniform int4 loads,
// weight computed ONCE per (edge, head) by lane (esub, hl), distributed via
// compile-time ds_swizzle. BitMode offset = (xor<<10)|(or<<5)|and, 5-bit
// fields; source lane = (lane & 0x18) | J within each 32-lane half (bit 5
// implicit) -> offset = (J<<5)|0x18.  [R14 bug: 0x38 leaked bit5 into the
// or-field, making or = J|1 -> even edges got odd edges' weights.]
// Pad entries (node 0) get w=0 via the eidx<deg predicate.
__global__ __launch_bounds__(256) void agg_kernel(const unsigned short* __restrict__ xpg,
                                                  const float* __restrict__ astp,
                                                  const float* __restrict__ adtp,
                                                  const int* __restrict__ cnt,
                                                  const int* __restrict__ ebuf,
                                                  float* __restrict__ hsum) {
    const int t = threadIdx.x;
    const int wave = t >> 6, lane = t & 63;
    const int g = blockIdx.x & 7;
    const int db = blockIdx.x >> 3;  // 0..2499
    const int cg = hstart_of(g + 1) - hstart_of(g);  // 6 or 7
    const int hl = lane >> 3;
    const int esub = lane & 7;
    const int co = (hl << 4) + esub * 2;  // element offset in 128-wide row
    const int dst = db * 4 + wave;        // 0..9999
    int deg = __builtin_amdgcn_readfirstlane(cnt[dst]);
    deg = (deg < ECAP) ? deg : ECAP;
    const int ebase = dst << 6;
    const float* ag = astp + g * (N_NODES * 8);
    const unsigned short* xg = xpg + (size_t)g * (N_NODES * 128);
    const float adv = adtp[g * (N_NODES * 8) + (dst << 3) + hl];
    // self loop (exp once per (dst, head))
    float lS = ag[(dst << 3) + hl] + adv;
    lS = fmaxf(lS, 0.2f * lS);
    const float wS = exp2f(lS);
    const unsigned pS = *(const unsigned*)(xg + (dst << 7) + co);
    float den = wS;
    float acc0 = wS * bits2f(pS << 16);
    float acc1 = wS * bits2f(pS & 0xffff0000u);
    for (int base = 0; base < deg; base += 8) {
        // uniform chunk src list (scalar loads)
        const int4 sA = *(const int4*)(ebuf + ebase + base);
        const int4 sB = *(const int4*)(ebuf + ebase + base + 4);
        // compute phase: w for (edge base+esub, head hl), computed ONCE
        const int eidx = base + esub;
        const int sE = ebuf[ebase + eidx];  // padded: always a valid index
        float l = ag[(sE << 3) + hl] + adv;
        l = fmaxf(l, 0.2f * l);
        const float w = (eidx < deg) ? exp2f(l) : 0.f;
        const int wi = __float_as_int(w);
        // accum phase: 8 edges; weight via swizzle src (lane&0x18)|J per half
#define STEP(J, SS)                                                                  \
        {                                                                            \
            const int sj = __builtin_amdgcn_readfirstlane(SS);                       \
            const float wj =                                                         \
                __int_as_float(__builtin_amdgcn_ds_swizzle(wi, ((J) << 5) | 0x18));  \
            const unsigned p = *(const unsigned*)(xg + (sj << 7) + co);              \
            den += wj;                                                               \
            acc0 = fmaf(wj, bits2f(p << 16), acc0);                                  \
            acc1 = fmaf(wj, bits2f(p & 0xffff0000u), acc1);                          \
        }
        STEP(0, sA.x) STEP(1, sA.y) STEP(2, sA.z) STEP(3, sA.w)
        STEP(4, sB.x) STEP(5, sB.y) STEP(6, sB.z) STEP(7, sB.w)
#undef STEP
    }
    const float inv = (hl < cg) ? (1.f / den) : 0.f;  // den>0: self loop
    float v0 = acc0 * inv, v1 = acc1 * inv;
    v0 += __shfl_xor(v0, 8);  v1 += __shfl_xor(v1, 8);
    v0 += __shfl_xor(v0, 16); v1 += __shfl_xor(v1, 16);
    v0 += __shfl_xor(v0, 32); v1 += __shfl_xor(v1, 32);
    if (lane < 8) {
        atomicAdd(&hsum[(dst << 4) + 2 * lane + 0], v0);
        atomicAdd(&hsum[(dst << 4) + 2 * lane + 1], v1);
    }
}

// ---- K5: per-graph mean pool (+ head mean + bias) + FC. One block per graph. ----
__global__ __launch_bounds__(256) void pool_kernel(const float* __restrict__ hsum,
                                                   const int* __restrict__ batch,
                                                   const float* __restrict__ bias,
                                                   const float* __restrict__ fc_w,
                                                   const float* __restrict__ fc_b,
                                                   float* __restrict__ out) {
    const int g = blockIdx.x;
    const int t = threadIdx.x;
    int a = 0, b = N_NODES;
    while (a < b) { int m = (a + b) >> 1; if (batch[m] < g) a = m + 1; else b = m; }
    const int lo = a;
    b = N_NODES;
    while (a < b) { int m = (a + b) >> 1; if (batch[m] < g + 1) a = m + 1; else b = m; }
    const int hi = a;
    const int cntn = hi - lo;
    float acc[16];
#pragma unroll
    for (int c = 0; c < 16; c++) acc[c] = 0.f;
    for (int n = lo + t; n < hi; n += 256) {
        const float4* r = (const float4*)(hsum + (n << 4));
        float4 v0 = r[0], v1 = r[1], v2 = r[2], v3 = r[3];
        acc[0] += v0.x; acc[1] += v0.y; acc[2] += v0.z; acc[3] += v0.w;
        acc[4] += v1.x; acc[5] += v1.y; acc[6] += v1.z; acc[7] += v1.w;
        acc[8] += v2.x; acc[9] += v2.y; acc[10] += v2.z; acc[11] += v2.w;
        acc[12] += v3.x; acc[13] += v3.y; acc[14] += v3.z; acc[15] += v3.w;
    }
    __shared__ float red[256][17];
#pragma unroll
    for (int c = 0; c < 16; c++) red[t][c] = acc[c];
    __syncthreads();
    for (int s = 128; s > 0; s >>= 1) {
        if (t < s)
#pragma unroll
            for (int c = 0; c < 16; c++) red[t][c] += red[t + s][c];
        __syncthreads();
    }
    __shared__ float pooled[16];
    if (t < 16) {
        float v = 0.f;
        if (cntn > 0) v = red[0][t] / ((float)cntn * (float)HEADS) + bias[t];
        pooled[t] = v;
    }
    __syncthreads();
    if (t < OUT_DIM) {
        float s = fc_b[t];
#pragma unroll
        for (int c = 0; c < HID; c++) s += pooled[c] * fc_w[c * OUT_DIM + t];
        out[g * OUT_DIM + t] = s;
    }
}

// ---- workspace layout (bytes) ----
#define XPG_OFF 0              /* 8*10000*8*16*2 = 20,480,000 */
#define ASTP_OFF 20480000      /* 8*10000*8*4    =  2,560,000 */
#define ADTP_OFF 23040000      /* 8*10000*8*4    =  2,560,000 */
#define XBF_OFF 25600000       /* 10000*128*2    =  2,560,000 (wt follows: OOB-read safe) */
#define WT_OFF 28160000        /* 800*128*2      =    204,800 */
#define EBUF_OFF 28364800      /* 10000*64*4     =  2,560,000 (zeroed: pad = node 0) */
#define CNT_OFF 30924800       /* 10000*4        =     40,000 (zeroed; contiguous w/ ebuf) */
#define HSUM_OFF 30964800      /* 10000*16*4     =    640,000 (zeroed in prep) */

extern "C" void kernel_launch(void* const* d_in, const int* in_sizes, int n_in,
                              void* d_out, int out_size, void* d_ws, size_t ws_size,
                              hipStream_t stream) {
    const float* x = (const float*)d_in[0];
    const int* ei = (const int*)d_in[1];
    const int* batch = (const int*)d_in[2];
    const float* W = (const float*)d_in[4];
    const float* a_src = (const float*)d_in[5];
    const float* a_dst = (const float*)d_in[6];
    const float* bias = (const float*)d_in[7];
    const float* fc_w = (const float*)d_in[8];
    const float* fc_b = (const float*)d_in[9];
    float* out = (float*)d_out;

    char* ws = (char*)d_ws;
    unsigned short* xpg = (unsigned short*)(ws + XPG_OFF);
    float* astp = (float*)(ws + ASTP_OFF);
    float* adtp = (float*)(ws + ADTP_OFF);
    unsigned short* xbf = (unsigned short*)(ws + XBF_OFF);
    unsigned short* wt = (unsigned short*)(ws + WT_OFF);
    int* ebuf = (int*)(ws + EBUF_OFF);
    int* cntc = (int*)(ws + CNT_OFF);
    float* hsum = (float*)(ws + HSUM_OFF);

    hipMemsetAsync(ws + EBUF_OFF, 0, 2560000 + 40000, stream);  // ebuf pad + cnt
    prep_kernel<<<2432, 256, 0, stream>>>(x, W, ei, xbf, wt, hsum, cntc, ebuf);
    gemm_mfma<<<dim3(10, (N_NODES + 127) / 128), 256, 0, stream>>>(
        xbf, wt, a_src, a_dst, xpg, astp, adtp);
    agg_kernel<<<8 * (N_NODES / 4), 256, 0, stream>>>(xpg, astp, adtp, cntc, ebuf, hsum);
    pool_kernel<<<N_GRAPHS, 256, 0, stream>>>(hsum, batch, bias, fc_w, fc_b, out);
}

// Round 16
// 175.935 us; speedup vs baseline: 17.7129x; 1.0393x over previous
//
#include <hip/hip_runtime.h>

#define N_NODES 10000
#define N_EDGES 160000
#define IN_DIM 128
#define HID 16
#define HEADS 50
#define OUT_DIM 10
#define N_GRAPHS 8
#define NHID (HEADS * HID) /* 800 */
#define ECAP 64  /* bucket capacity per dst; Poisson(16), P(deg>63) ~ 1e-20 */

// 8 head-groups: grp g owns heads [hstart(g), hstart(g+1)), 6 or 7 heads.
static __device__ __forceinline__ int hstart_of(int g) { return (g * 25) >> 2; }

typedef __attribute__((ext_vector_type(8))) short bfrag;   // 8 bf16 (4 VGPRs)
typedef __attribute__((ext_vector_type(4))) float ffrag;   // 4 fp32 acc

#define LOG2E 1.44269504088896340736f

// ---- bf16 helpers (self-contained, RNE) ----
static __device__ __forceinline__ unsigned short f2bf(float f) {
    union { float f; unsigned u; } v; v.f = f;
    unsigned u = v.u;
    unsigned r = (u + 0x7fffu + ((u >> 16) & 1u)) >> 16;
    return (unsigned short)r;
}
static __device__ __forceinline__ float bits2f(unsigned u) {
    union { unsigned u; float f; } v; v.u = u;
    return v.f;
}

// ---- K0: fused parallel prep: xcast | wcast(transpose) | hsum zero | edge APPEND ----
// blocks [0,1250): xbf = bf16(x)                (320000 float4s)
// blocks [1250,1650): wt[n][k] = bf16(W[k][n])  (102400 elems)
// blocks [1650,1807): hsum = 0                  (40000 float4s)
// blocks [1807,2432): ebuf[dst*64 + slot] = src (slot = atomicAdd(cnt[dst],1))
// ebuf+cnt pre-zeroed by ONE memset: pad slots = node 0 (valid; weight-masked).
__global__ __launch_bounds__(256) void prep_kernel(const float* __restrict__ x,
                                                   const float* __restrict__ W,
                                                   const int* __restrict__ ei,
                                                   unsigned short* __restrict__ xbf,
                                                   unsigned short* __restrict__ wt,
                                                   float* __restrict__ hsum,
                                                   int* __restrict__ cnt,
                                                   int* __restrict__ ebuf) {
    const int bid = blockIdx.x, tid = threadIdx.x;
    if (bid < 1250) {
        int t = bid * 256 + tid;  // exactly 320000
        float4 v = ((const float4*)x)[t];
        ushort4 o;
        o.x = f2bf(v.x); o.y = f2bf(v.y); o.z = f2bf(v.z); o.w = f2bf(v.w);
        ((ushort4*)xbf)[t] = o;
    } else if (bid < 1650) {
        int t = (bid - 1250) * 256 + tid;  // exactly 102400
        int n = t >> 7, k = t & 127;
        wt[t] = f2bf(W[k * NHID + n]);
    } else if (bid < 1807) {
        int t = (bid - 1650) * 256 + tid;
        if (t < 40000) ((float4*)hsum)[t] = make_float4(0.f, 0.f, 0.f, 0.f);
    } else {
        int e = (bid - 1807) * 256 + tid;
        if (e < N_EDGES) {
            int d = ei[N_EDGES + e];
            int slot = atomicAdd(&cnt[d], 1);
            if (slot < ECAP) ebuf[(d << 6) + slot] = ei[e];  // guard: no OOB ever
        }
    }
}

// ---- K1: MFMA bf16 GEMM, LDS-free, alpha fused (pre-scaled by log2e) ----
// grid (10, 79), block 256 = 4 waves; wave: 32 rows x 80 cols = 2x5 tiles.
__global__ __launch_bounds__(256) void gemm_mfma(const unsigned short* __restrict__ xbf,
                                                 const unsigned short* __restrict__ wt,
                                                 const float* __restrict__ a_src,
                                                 const float* __restrict__ a_dst,
                                                 unsigned short* __restrict__ xpg,
                                                 float* __restrict__ astp,
                                                 float* __restrict__ adtp) {
    const int tid = threadIdx.x;
    const int wave = tid >> 6, lane = tid & 63;
    const int q = lane >> 4, r = lane & 15;
    const int m0 = blockIdx.y * 128 + wave * 32;
    const int h0 = blockIdx.x * 5;
    ffrag zf = {0.f, 0.f, 0.f, 0.f};
    ffrag acc[2][5];
#pragma unroll
    for (int mt = 0; mt < 2; mt++)
#pragma unroll
        for (int nt = 0; nt < 5; nt++) acc[mt][nt] = zf;

    // A reads may overrun past node 9999 (stores guarded); xbf is followed by
    // wt in the workspace so reads stay inside the allocation.
#pragma unroll
    for (int kc = 0; kc < IN_DIM; kc += 32) {
        bfrag a[2], b[5];
#pragma unroll
        for (int mt = 0; mt < 2; mt++)
            a[mt] = *(const bfrag*)(xbf + (m0 + mt * 16 + r) * IN_DIM + kc + q * 8);
#pragma unroll
        for (int nt = 0; nt < 5; nt++)
            b[nt] = *(const bfrag*)(wt + ((h0 + nt) * 16 + r) * IN_DIM + kc + q * 8);
#pragma unroll
        for (int mt = 0; mt < 2; mt++)
#pragma unroll
            for (int nt = 0; nt < 5; nt++)
                acc[mt][nt] = __builtin_amdgcn_mfma_f32_16x16x32_bf16(a[mt], b[nt],
                                                                      acc[mt][nt], 0, 0, 0);
    }
#pragma unroll
    for (int nt = 0; nt < 5; nt++) {
        const int h = h0 + nt;
        const int g = (8 * h + 7) / 50;
        const int hl = h - hstart_of(g);
        const float asw = a_src[h * HID + r] * LOG2E;
        const float adw = a_dst[h * HID + r] * LOG2E;
        unsigned short* xg = xpg + (size_t)g * (N_NODES * 128);
        float* ag = astp + g * (N_NODES * 8);
        float* dg = adtp + g * (N_NODES * 8);
#pragma unroll
        for (int mt = 0; mt < 2; mt++) {
            ffrag d = acc[mt][nt];  // rows m = m0+mt*16+q*4+i, col r
            float s[4], w[4];
#pragma unroll
            for (int i = 0; i < 4; i++) { s[i] = d[i] * asw; w[i] = d[i] * adw; }
#pragma unroll
            for (int off = 1; off < 16; off <<= 1) {
#pragma unroll
                for (int i = 0; i < 4; i++) {
                    s[i] += __shfl_xor(s[i], off);
                    w[i] += __shfl_xor(w[i], off);
                }
            }
#pragma unroll
            for (int i = 0; i < 4; i++) {
                const int node = m0 + mt * 16 + q * 4 + i;
                if (node < N_NODES) {
                    xg[node * 128 + hl * 16 + r] = f2bf(d[i]);
                    if (r == 0) {
                        ag[(node << 3) + hl] = s[i];
                        dg[(node << 3) + hl] = w[i];
                    }
                }
            }
        }
    }
}

// ---- K4: chunk-deduped aggregation over zero-padded bucket lists ----
// grid 20000 = 8 grps x 2500 (blockIdx&7 -> XCD; slice L2-resident). Wave owns
// dst = db*4+wave, with dst wrapped in readfirstlane so the compiler proves
// wave-uniformity: chunk src lists become s_load_dwordx4, per-STEP src
// indices are SGPRs (readfirstlane folds to SALU), and all table bases are
// saddr-form. Weight computed ONCE per (edge, head) by lane (esub, hl),
// distributed via compile-time ds_swizzle (src lane (lane&0x18)|J per
// 32-half; offset = (J<<5)|0x18). Pad entries (node 0) get w=0 via the
// eidx<deg predicate.
__global__ __launch_bounds__(256) void agg_kernel(const unsigned short* __restrict__ xpg,
                                                  const float* __restrict__ astp,
                                                  const float* __restrict__ adtp,
                                                  const int* __restrict__ cnt,
                                                  const int* __restrict__ ebuf,
                                                  float* __restrict__ hsum) {
    const int t = threadIdx.x;
    const int wave = t >> 6, lane = t & 63;
    const int g = blockIdx.x & 7;
    const int db = blockIdx.x >> 3;  // 0..2499
    const int cg = hstart_of(g + 1) - hstart_of(g);  // 6 or 7
    const int hl = lane >> 3;
    const int esub = lane & 7;
    const int co = (hl << 4) + esub * 2;  // element offset in 128-wide row
    const int dst = __builtin_amdgcn_readfirstlane(db * 4 + wave);  // scalar dst
    int deg = __builtin_amdgcn_readfirstlane(cnt[dst]);
    deg = (deg < ECAP) ? deg : ECAP;
    const int ebase = dst << 6;  // scalar
    const float* ag = astp + g * (N_NODES * 8);
    const unsigned short* xg = xpg + (size_t)g * (N_NODES * 128);
    const float adv = adtp[g * (N_NODES * 8) + (dst << 3) + hl];
    // self loop (exp once per (dst, head))
    float lS = ag[(dst << 3) + hl] + adv;
    lS = fmaxf(lS, 0.2f * lS);
    const float wS = exp2f(lS);
    const unsigned pS = *(const unsigned*)(xg + (dst << 7) + co);
    float den = wS;
    float acc0 = wS * bits2f(pS << 16);
    float acc1 = wS * bits2f(pS & 0xffff0000u);
    for (int base = 0; base < deg; base += 8) {
        // uniform chunk src list (scalar address -> s_load_dwordx4)
        const int4 sA = *(const int4*)(ebuf + ebase + base);
        const int4 sB = *(const int4*)(ebuf + ebase + base + 4);
        // compute phase: w for (edge base+esub, head hl), computed ONCE
        const int eidx = base + esub;
        const int sE = ebuf[ebase + eidx];  // padded: always a valid index
        float l = ag[(sE << 3) + hl] + adv;
        l = fmaxf(l, 0.2f * l);
        const float w = (eidx < deg) ? exp2f(l) : 0.f;
        const int wi = __float_as_int(w);
        // accum phase: 8 edges; weight via swizzle src (lane&0x18)|J per half
#define STEP(J, SS)                                                                  \
        {                                                                            \
            const int sj = __builtin_amdgcn_readfirstlane(SS);                       \
            const float wj =                                                         \
                __int_as_float(__builtin_amdgcn_ds_swizzle(wi, ((J) << 5) | 0x18));  \
            const unsigned p = *(const unsigned*)(xg + (sj << 7) + co);              \
            den += wj;                                                               \
            acc0 = fmaf(wj, bits2f(p << 16), acc0);                                  \
            acc1 = fmaf(wj, bits2f(p & 0xffff0000u), acc1);                          \
        }
        STEP(0, sA.x) STEP(1, sA.y) STEP(2, sA.z) STEP(3, sA.w)
        STEP(4, sB.x) STEP(5, sB.y) STEP(6, sB.z) STEP(7, sB.w)
#undef STEP
    }
    const float inv = (hl < cg) ? (1.f / den) : 0.f;  // den>0: self loop
    float v0 = acc0 * inv, v1 = acc1 * inv;
    v0 += __shfl_xor(v0, 8);  v1 += __shfl_xor(v1, 8);
    v0 += __shfl_xor(v0, 16); v1 += __shfl_xor(v1, 16);
    v0 += __shfl_xor(v0, 32); v1 += __shfl_xor(v1, 32);
    if (lane < 8) {
        atomicAdd(&hsum[(dst << 4) + 2 * lane + 0], v0);
        atomicAdd(&hsum[(dst << 4) + 2 * lane + 1], v1);
    }
}

// ---- K5: per-graph mean pool (+ head mean + bias) + FC. One block per graph. ----
__global__ __launch_bounds__(256) void pool_kernel(const float* __restrict__ hsum,
                                                   const int* __restrict__ batch,
                                                   const float* __restrict__ bias,
                                                   const float* __restrict__ fc_w,
                                                   const float* __restrict__ fc_b,
                                                   float* __restrict__ out) {
    const int g = blockIdx.x;
    const int t = threadIdx.x;
    int a = 0, b = N_NODES;
    while (a < b) { int m = (a + b) >> 1; if (batch[m] < g) a = m + 1; else b = m; }
    const int lo = a;
    b = N_NODES;
    while (a < b) { int m = (a + b) >> 1; if (batch[m] < g + 1) a = m + 1; else b = m; }
    const int hi = a;
    const int cntn = hi - lo;
    float acc[16];
#pragma unroll
    for (int c = 0; c < 16; c++) acc[c] = 0.f;
    for (int n = lo + t; n < hi; n += 256) {
        const float4* r = (const float4*)(hsum + (n << 4));
        float4 v0 = r[0], v1 = r[1], v2 = r[2], v3 = r[3];
        acc[0] += v0.x; acc[1] += v0.y; acc[2] += v0.z; acc[3] += v0.w;
        acc[4] += v1.x; acc[5] += v1.y; acc[6] += v1.z; acc[7] += v1.w;
        acc[8] += v2.x; acc[9] += v2.y; acc[10] += v2.z; acc[11] += v2.w;
        acc[12] += v3.x; acc[13] += v3.y; acc[14] += v3.z; acc[15] += v3.w;
    }
    __shared__ float red[256][17];
#pragma unroll
    for (int c = 0; c < 16; c++) red[t][c] = acc[c];
    __syncthreads();
    for (int s = 128; s > 0; s >>= 1) {
        if (t < s)
#pragma unroll
            for (int c = 0; c < 16; c++) red[t][c] += red[t + s][c];
        __syncthreads();
    }
    __shared__ float pooled[16];
    if (t < 16) {
        float v = 0.f;
        if (cntn > 0) v = red[0][t] / ((float)cntn * (float)HEADS) + bias[t];
        pooled[t] = v;
    }
    __syncthreads();
    if (t < OUT_DIM) {
        float s = fc_b[t];
#pragma unroll
        for (int c = 0; c < HID; c++) s += pooled[c] * fc_w[c * OUT_DIM + t];
        out[g * OUT_DIM + t] = s;
    }
}

// ---- workspace layout (bytes) ----
#define XPG_OFF 0              /* 8*10000*8*16*2 = 20,480,000 */
#define ASTP_OFF 20480000      /* 8*10000*8*4    =  2,560,000 */
#define ADTP_OFF 23040000      /* 8*10000*8*4    =  2,560,000 */
#define XBF_OFF 25600000       /* 10000*128*2    =  2,560,000 (wt follows: OOB-read safe) */
#define WT_OFF 28160000        /* 800*128*2      =    204,800 */
#define EBUF_OFF 28364800      /* 10000*64*4     =  2,560,000 (zeroed: pad = node 0) */
#define CNT_OFF 30924800       /* 10000*4        =     40,000 (zeroed; contiguous w/ ebuf) */
#define HSUM_OFF 30964800      /* 10000*16*4     =    640,000 (zeroed in prep) */

extern "C" void kernel_launch(void* const* d_in, const int* in_sizes, int n_in,
                              void* d_out, int out_size, void* d_ws, size_t ws_size,
                              hipStream_t stream) {
    const float* x = (const float*)d_in[0];
    const int* ei = (const int*)d_in[1];
    const int* batch = (const int*)d_in[2];
    const float* W = (const float*)d_in[4];
    const float* a_src = (const float*)d_in[5];
    const float* a_dst = (const float*)d_in[6];
    const float* bias = (const float*)d_in[7];
    const float* fc_w = (const float*)d_in[8];
    const float* fc_b = (const float*)d_in[9];
    float* out = (float*)d_out;

    char* ws = (char*)d_ws;
    unsigned short* xpg = (unsigned short*)(ws + XPG_OFF);
    float* astp = (float*)(ws + ASTP_OFF);
    float* adtp = (float*)(ws + ADTP_OFF);
    unsigned short* xbf = (unsigned short*)(ws + XBF_OFF);
    unsigned short* wt = (unsigned short*)(ws + WT_OFF);
    int* ebuf = (int*)(ws + EBUF_OFF);
    int* cntc = (int*)(ws + CNT_OFF);
    float* hsum = (float*)(ws + HSUM_OFF);

    hipMemsetAsync(ws + EBUF_OFF, 0, 2560000 + 40000, stream);  // ebuf pad + cnt
    prep_kernel<<<2432, 256, 0, stream>>>(x, W, ei, xbf, wt, hsum, cntc, ebuf);
    gemm_mfma<<<dim3(10, (N_NODES + 127) / 128), 256, 0, stream>>>(
        xbf, wt, a_src, a_dst, xpg, astp, adtp);
    agg_kernel<<<8 * (N_NODES / 4), 256, 0, stream>>>(xpg, astp, adtp, cntc, ebuf, hsum);
    pool_kernel<<<N_GRAPHS, 256, 0, stream>>>(hsum, batch, bias, fc_w, fc_b, out);
}

// Round 17
// 172.370 us; speedup vs baseline: 18.0792x; 1.0207x over previous
//
#include <hip/hip_runtime.h>

#define N_NODES 10000
#define N_EDGES 160000
#define IN_DIM 128
#define HID 16
#define HEADS 50
#define OUT_DIM 10
#define N_GRAPHS 8
#define NHID (HEADS * HID) /* 800 */
#define ECAP 64  /* bucket capacity per dst; Poisson(16), P(deg>63) ~ 1e-20 */

// 8 head-groups: grp g owns heads [hstart(g), hstart(g+1)), 6 or 7 heads.
static __device__ __forceinline__ int hstart_of(int g) { return (g * 25) >> 2; }

typedef __attribute__((ext_vector_type(8))) short bfrag;   // 8 bf16 (4 VGPRs)
typedef __attribute__((ext_vector_type(4))) float ffrag;   // 4 fp32 acc

#define LOG2E 1.44269504088896340736f

// ---- bf16 helpers (self-contained, RNE) ----
static __device__ __forceinline__ unsigned short f2bf(float f) {
    union { float f; unsigned u; } v; v.f = f;
    unsigned u = v.u;
    unsigned r = (u + 0x7fffu + ((u >> 16) & 1u)) >> 16;
    return (unsigned short)r;
}
static __device__ __forceinline__ float bits2f(unsigned u) {
    union { unsigned u; float f; } v; v.u = u;
    return v.f;
}

// ---- K0: fused parallel prep: xcast | wcast(transpose) | hsum zero | edge APPEND ----
// blocks [0,1250): xbf = bf16(x)                (320000 float4s)
// blocks [1250,1650): wt[n][k] = bf16(W[k][n])  (102400 elems)
// blocks [1650,1807): hsum = 0                  (40000 float4s)
// blocks [1807,2432): ebuf[dst*64 + slot] = src (slot = atomicAdd(cnt[dst],1))
// ebuf+cnt pre-zeroed by ONE memset: pad slots = node 0 (valid; weight-masked).
__global__ __launch_bounds__(256) void prep_kernel(const float* __restrict__ x,
                                                   const float* __restrict__ W,
                                                   const int* __restrict__ ei,
                                                   unsigned short* __restrict__ xbf,
                                                   unsigned short* __restrict__ wt,
                                                   float* __restrict__ hsum,
                                                   int* __restrict__ cnt,
                                                   int* __restrict__ ebuf) {
    const int bid = blockIdx.x, tid = threadIdx.x;
    if (bid < 1250) {
        int t = bid * 256 + tid;  // exactly 320000
        float4 v = ((const float4*)x)[t];
        ushort4 o;
        o.x = f2bf(v.x); o.y = f2bf(v.y); o.z = f2bf(v.z); o.w = f2bf(v.w);
        ((ushort4*)xbf)[t] = o;
    } else if (bid < 1650) {
        int t = (bid - 1250) * 256 + tid;  // exactly 102400
        int n = t >> 7, k = t & 127;
        wt[t] = f2bf(W[k * NHID + n]);
    } else if (bid < 1807) {
        int t = (bid - 1650) * 256 + tid;
        if (t < 40000) ((float4*)hsum)[t] = make_float4(0.f, 0.f, 0.f, 0.f);
    } else {
        int e = (bid - 1807) * 256 + tid;
        if (e < N_EDGES) {
            int d = ei[N_EDGES + e];
            int slot = atomicAdd(&cnt[d], 1);
            if (slot < ECAP) ebuf[(d << 6) + slot] = ei[e];  // guard: no OOB ever
        }
    }
}

// ---- K1: MFMA bf16 GEMM, LDS-free, alpha fused (pre-scaled by log2e) ----
// grid (10, 79), block 256 = 4 waves; wave: 32 rows x 80 cols = 2x5 tiles.
__global__ __launch_bounds__(256) void gemm_mfma(const unsigned short* __restrict__ xbf,
                                                 const unsigned short* __restrict__ wt,
                                                 const float* __restrict__ a_src,
                                                 const float* __restrict__ a_dst,
                                                 unsigned short* __restrict__ xpg,
                                                 float* __restrict__ astp,
                                                 float* __restrict__ adtp) {
    const int tid = threadIdx.x;
    const int wave = tid >> 6, lane = tid & 63;
    const int q = lane >> 4, r = lane & 15;
    const int m0 = blockIdx.y * 128 + wave * 32;
    const int h0 = blockIdx.x * 5;
    ffrag zf = {0.f, 0.f, 0.f, 0.f};
    ffrag acc[2][5];
#pragma unroll
    for (int mt = 0; mt < 2; mt++)
#pragma unroll
        for (int nt = 0; nt < 5; nt++) acc[mt][nt] = zf;

    // A reads may overrun past node 9999 (stores guarded); xbf is followed by
    // wt in the workspace so reads stay inside the allocation.
#pragma unroll
    for (int kc = 0; kc < IN_DIM; kc += 32) {
        bfrag a[2], b[5];
#pragma unroll
        for (int mt = 0; mt < 2; mt++)
            a[mt] = *(const bfrag*)(xbf + (m0 + mt * 16 + r) * IN_DIM + kc + q * 8);
#pragma unroll
        for (int nt = 0; nt < 5; nt++)
            b[nt] = *(const bfrag*)(wt + ((h0 + nt) * 16 + r) * IN_DIM + kc + q * 8);
#pragma unroll
        for (int mt = 0; mt < 2; mt++)
#pragma unroll
            for (int nt = 0; nt < 5; nt++)
                acc[mt][nt] = __builtin_amdgcn_mfma_f32_16x16x32_bf16(a[mt], b[nt],
                                                                      acc[mt][nt], 0, 0, 0);
    }
#pragma unroll
    for (int nt = 0; nt < 5; nt++) {
        const int h = h0 + nt;
        const int g = (8 * h + 7) / 50;
        const int hl = h - hstart_of(g);
        const float asw = a_src[h * HID + r] * LOG2E;
        const float adw = a_dst[h * HID + r] * LOG2E;
        unsigned short* xg = xpg + (size_t)g * (N_NODES * 128);
        float* ag = astp + g * (N_NODES * 8);
        float* dg = adtp + g * (N_NODES * 8);
#pragma unroll
        for (int mt = 0; mt < 2; mt++) {
            ffrag d = acc[mt][nt];  // rows m = m0+mt*16+q*4+i, col r
            float s[4], w[4];
#pragma unroll
            for (int i = 0; i < 4; i++) { s[i] = d[i] * asw; w[i] = d[i] * adw; }
#pragma unroll
            for (int off = 1; off < 16; off <<= 1) {
#pragma unroll
                for (int i = 0; i < 4; i++) {
                    s[i] += __shfl_xor(s[i], off);
                    w[i] += __shfl_xor(w[i], off);
                }
            }
#pragma unroll
            for (int i = 0; i < 4; i++) {
                const int node = m0 + mt * 16 + q * 4 + i;
                if (node < N_NODES) {
                    xg[node * 128 + hl * 16 + r] = f2bf(d[i]);
                    if (r == 0) {
                        ag[(node << 3) + hl] = s[i];
                        dg[(node << 3) + hl] = w[i];
                    }
                }
            }
        }
    }
}

// ---- K4: chunk-deduped aggregation, TWO dsts per wave (ILP-doubled) ----
// grid 10000 = 8 grps x 1250 (blockIdx&7 -> XCD; slice L2-resident). Wave owns
// dsts {2p, 2p+1} (p = db*4+wave), fused in ONE chunk loop (count = max of the
// two chunk counts): two independent dependent-chains interleave, halving
// exposed latency. Zero-padded buckets make over-reading the shorter dst safe
// (pad = node 0, weight masked by eidx<deg). Weights deduped per (edge, head)
// and distributed via compile-time ds_swizzle (src lane (lane&0x18)|J per
// 32-half: offset = (J<<5)|0x18). Reduction tree is lane-symmetric: lanes 0-7
// commit dstA, lanes 8-15 commit dstB.
__global__ __launch_bounds__(256) void agg_kernel(const unsigned short* __restrict__ xpg,
                                                  const float* __restrict__ astp,
                                                  const float* __restrict__ adtp,
                                                  const int* __restrict__ cnt,
                                                  const int* __restrict__ ebuf,
                                                  float* __restrict__ hsum) {
    const int t = threadIdx.x;
    const int wave = t >> 6, lane = t & 63;
    const int g = blockIdx.x & 7;
    const int db = blockIdx.x >> 3;  // 0..1249
    const int cg = hstart_of(g + 1) - hstart_of(g);  // 6 or 7
    const int hl = lane >> 3;
    const int esub = lane & 7;
    const int co = (hl << 4) + esub * 2;  // element offset in 128-wide row
    const int p = db * 4 + wave;          // pair index 0..4999
    const int dstA = __builtin_amdgcn_readfirstlane(p * 2);
    const int dstB = dstA + 1;
    int degA = __builtin_amdgcn_readfirstlane(cnt[dstA]);
    int degB = __builtin_amdgcn_readfirstlane(cnt[dstB]);
    degA = (degA < ECAP) ? degA : ECAP;
    degB = (degB < ECAP) ? degB : ECAP;
    const int ebA = dstA << 6, ebB = dstB << 6;  // scalar
    const float* ag = astp + g * (N_NODES * 8);
    const unsigned short* xg = xpg + (size_t)g * (N_NODES * 128);
    const float advA = adtp[g * (N_NODES * 8) + (dstA << 3) + hl];
    const float advB = adtp[g * (N_NODES * 8) + (dstB << 3) + hl];
    // self loops (exp once per (dst, head))
    float lSA = ag[(dstA << 3) + hl] + advA;
    float lSB = ag[(dstB << 3) + hl] + advB;
    lSA = fmaxf(lSA, 0.2f * lSA);
    lSB = fmaxf(lSB, 0.2f * lSB);
    const float wSA = exp2f(lSA), wSB = exp2f(lSB);
    const unsigned pSA = *(const unsigned*)(xg + (dstA << 7) + co);
    const unsigned pSB = *(const unsigned*)(xg + (dstB << 7) + co);
    float denA = wSA, denB = wSB;
    float a0 = wSA * bits2f(pSA << 16), a1 = wSA * bits2f(pSA & 0xffff0000u);
    float b0 = wSB * bits2f(pSB << 16), b1 = wSB * bits2f(pSB & 0xffff0000u);
    const int degM = (degA > degB) ? degA : degB;
    for (int base = 0; base < degM; base += 8) {
        // uniform chunk src lists (scalar addresses -> s_load_dwordx4)
        const int4 sA0 = *(const int4*)(ebuf + ebA + base);
        const int4 sA1 = *(const int4*)(ebuf + ebA + base + 4);
        const int4 sB0 = *(const int4*)(ebuf + ebB + base);
        const int4 sB1 = *(const int4*)(ebuf + ebB + base + 4);
        // compute phase: w for (edge base+esub, head hl), computed ONCE per dst
        const int eidx = base + esub;
        const int sEA = ebuf[ebA + eidx];  // padded: always valid
        const int sEB = ebuf[ebB + eidx];
        float lA = ag[(sEA << 3) + hl] + advA;
        float lB = ag[(sEB << 3) + hl] + advB;
        lA = fmaxf(lA, 0.2f * lA);
        lB = fmaxf(lB, 0.2f * lB);
        const float wA = (eidx < degA) ? exp2f(lA) : 0.f;
        const float wB = (eidx < degB) ? exp2f(lB) : 0.f;
        const int wiA = __float_as_int(wA);
        const int wiB = __float_as_int(wB);
        // accum phase: 8 edges x 2 dsts; weights via swizzle (lane&0x18)|J
#define STEP(J, SSA, SSB)                                                             \
        {                                                                             \
            const int sjA = __builtin_amdgcn_readfirstlane(SSA);                      \
            const int sjB = __builtin_amdgcn_readfirstlane(SSB);                      \
            const float wjA =                                                         \
                __int_as_float(__builtin_amdgcn_ds_swizzle(wiA, ((J) << 5) | 0x18));  \
            const float wjB =                                                         \
                __int_as_float(__builtin_amdgcn_ds_swizzle(wiB, ((J) << 5) | 0x18));  \
            const unsigned pA = *(const unsigned*)(xg + (sjA << 7) + co);             \
            const unsigned pB = *(const unsigned*)(xg + (sjB << 7) + co);             \
            denA += wjA;                                                              \
            denB += wjB;                                                              \
            a0 = fmaf(wjA, bits2f(pA << 16), a0);                                     \
            a1 = fmaf(wjA, bits2f(pA & 0xffff0000u), a1);                             \
            b0 = fmaf(wjB, bits2f(pB << 16), b0);                                     \
            b1 = fmaf(wjB, bits2f(pB & 0xffff0000u), b1);                             \
        }
        STEP(0, sA0.x, sB0.x) STEP(1, sA0.y, sB0.y)
        STEP(2, sA0.z, sB0.z) STEP(3, sA0.w, sB0.w)
        STEP(4, sA1.x, sB1.x) STEP(5, sA1.y, sB1.y)
        STEP(6, sA1.z, sB1.z) STEP(7, sA1.w, sB1.w)
#undef STEP
    }
    const float invA = (hl < cg) ? (1.f / denA) : 0.f;  // den>0: self loop
    const float invB = (hl < cg) ? (1.f / denB) : 0.f;
    float vA0 = a0 * invA, vA1 = a1 * invA;
    float vB0 = b0 * invB, vB1 = b1 * invB;
    // butterfly over bits 3..5: every lane ends with its (lane&7)-group sum
    vA0 += __shfl_xor(vA0, 8);  vA1 += __shfl_xor(vA1, 8);
    vB0 += __shfl_xor(vB0, 8);  vB1 += __shfl_xor(vB1, 8);
    vA0 += __shfl_xor(vA0, 16); vA1 += __shfl_xor(vA1, 16);
    vB0 += __shfl_xor(vB0, 16); vB1 += __shfl_xor(vB1, 16);
    vA0 += __shfl_xor(vA0, 32); vA1 += __shfl_xor(vA1, 32);
    vB0 += __shfl_xor(vB0, 32); vB1 += __shfl_xor(vB1, 32);
    const int l8 = lane & 7;
    if (lane < 8) {
        atomicAdd(&hsum[(dstA << 4) + 2 * l8 + 0], vA0);
        atomicAdd(&hsum[(dstA << 4) + 2 * l8 + 1], vA1);
    } else if (lane < 16) {
        atomicAdd(&hsum[(dstB << 4) + 2 * l8 + 0], vB0);
        atomicAdd(&hsum[(dstB << 4) + 2 * l8 + 1], vB1);
    }
}

// ---- K5: per-graph mean pool (+ head mean + bias) + FC. One block per graph. ----
__global__ __launch_bounds__(256) void pool_kernel(const float* __restrict__ hsum,
                                                   const int* __restrict__ batch,
                                                   const float* __restrict__ bias,
                                                   const float* __restrict__ fc_w,
                                                   const float* __restrict__ fc_b,
                                                   float* __restrict__ out) {
    const int g = blockIdx.x;
    const int t = threadIdx.x;
    int a = 0, b = N_NODES;
    while (a < b) { int m = (a + b) >> 1; if (batch[m] < g) a = m + 1; else b = m; }
    const int lo = a;
    b = N_NODES;
    while (a < b) { int m = (a + b) >> 1; if (batch[m] < g + 1) a = m + 1; else b = m; }
    const int hi = a;
    const int cntn = hi - lo;
    float acc[16];
#pragma unroll
    for (int c = 0; c < 16; c++) acc[c] = 0.f;
    for (int n = lo + t; n < hi; n += 256) {
        const float4* r = (const float4*)(hsum + (n << 4));
        float4 v0 = r[0], v1 = r[1], v2 = r[2], v3 = r[3];
        acc[0] += v0.x; acc[1] += v0.y; acc[2] += v0.z; acc[3] += v0.w;
        acc[4] += v1.x; acc[5] += v1.y; acc[6] += v1.z; acc[7] += v1.w;
        acc[8] += v2.x; acc[9] += v2.y; acc[10] += v2.z; acc[11] += v2.w;
        acc[12] += v3.x; acc[13] += v3.y; acc[14] += v3.z; acc[15] += v3.w;
    }
    __shared__ float red[256][17];
#pragma unroll
    for (int c = 0; c < 16; c++) red[t][c] = acc[c];
    __syncthreads();
    for (int s = 128; s > 0; s >>= 1) {
        if (t < s)
#pragma unroll
            for (int c = 0; c < 16; c++) red[t][c] += red[t + s][c];
        __syncthreads();
    }
    __shared__ float pooled[16];
    if (t < 16) {
        float v = 0.f;
        if (cntn > 0) v = red[0][t] / ((float)cntn * (float)HEADS) + bias[t];
        pooled[t] = v;
    }
    __syncthreads();
    if (t < OUT_DIM) {
        float s = fc_b[t];
#pragma unroll
        for (int c = 0; c < HID; c++) s += pooled[c] * fc_w[c * OUT_DIM + t];
        out[g * OUT_DIM + t] = s;
    }
}

// ---- workspace layout (bytes) ----
#define XPG_OFF 0              /* 8*10000*8*16*2 = 20,480,000 */
#define ASTP_OFF 20480000      /* 8*10000*8*4    =  2,560,000 */
#define ADTP_OFF 23040000      /* 8*10000*8*4    =  2,560,000 */
#define XBF_OFF 25600000       /* 10000*128*2    =  2,560,000 (wt follows: OOB-read safe) */
#define WT_OFF 28160000        /* 800*128*2      =    204,800 */
#define EBUF_OFF 28364800      /* 10000*64*4     =  2,560,000 (zeroed: pad = node 0) */
#define CNT_OFF 30924800       /* 10000*4        =     40,000 (zeroed; contiguous w/ ebuf) */
#define HSUM_OFF 30964800      /* 10000*16*4     =    640,000 (zeroed in prep) */

extern "C" void kernel_launch(void* const* d_in, const int* in_sizes, int n_in,
                              void* d_out, int out_size, void* d_ws, size_t ws_size,
                              hipStream_t stream) {
    const float* x = (const float*)d_in[0];
    const int* ei = (const int*)d_in[1];
    const int* batch = (const int*)d_in[2];
    const float* W = (const float*)d_in[4];
    const float* a_src = (const float*)d_in[5];
    const float* a_dst = (const float*)d_in[6];
    const float* bias = (const float*)d_in[7];
    const float* fc_w = (const float*)d_in[8];
    const float* fc_b = (const float*)d_in[9];
    float* out = (float*)d_out;

    char* ws = (char*)d_ws;
    unsigned short* xpg = (unsigned short*)(ws + XPG_OFF);
    float* astp = (float*)(ws + ASTP_OFF);
    float* adtp = (float*)(ws + ADTP_OFF);
    unsigned short* xbf = (unsigned short*)(ws + XBF_OFF);
    unsigned short* wt = (unsigned short*)(ws + WT_OFF);
    int* ebuf = (int*)(ws + EBUF_OFF);
    int* cntc = (int*)(ws + CNT_OFF);
    float* hsum = (float*)(ws + HSUM_OFF);

    hipMemsetAsync(ws + EBUF_OFF, 0, 2560000 + 40000, stream);  // ebuf pad + cnt
    prep_kernel<<<2432, 256, 0, stream>>>(x, W, ei, xbf, wt, hsum, cntc, ebuf);
    gemm_mfma<<<dim3(10, (N_NODES + 127) / 128), 256, 0, stream>>>(
        xbf, wt, a_src, a_dst, xpg, astp, adtp);
    agg_kernel<<<8 * (N_NODES / 8), 256, 0, stream>>>(xpg, astp, adtp, cntc, ebuf, hsum);
    pool_kernel<<<N_GRAPHS, 256, 0, stream>>>(hsum, batch, bias, fc_w, fc_b, out);
}